// Round 1
// baseline (694.143 us; speedup 1.0000x reference)
//
#include <hip/hip_runtime.h>

#define LBL 64
#define TT 1024
#define BB 256
#define BOS 62
#define EOS 63
#define NEGV -10000.0f

// One block per sentence. 256 threads = 4 waves (one per SIMD).
// lane = next-label n (0..63), wave w owns prev-labels [16w, 16w+16).
// fv lives in registers (replicated across waves); backpointers live in LDS.
__global__ __launch_bounds__(256, 1) void viterbi_kernel(
    const float* __restrict__ X, const float* __restrict__ trans,
    float* __restrict__ out)
{
    __shared__ unsigned char bp[TT][LBL];      // 64 KiB backpointers
    __shared__ float2 part[2][4][LBL];         // 4 KiB double-buffered partials
    __shared__ float termv[LBL];
    __shared__ unsigned char path_s[TT];

    const int tid  = threadIdx.x;
    const int b    = blockIdx.x;
    const int lane = tid & 63;
    const int w    = tid >> 6;
    // wave-uniform (SGPR) base of this wave's prev range, for v_readlane
    const int wbase = ((__builtin_amdgcn_readfirstlane(tid) >> 6) << 4);

    // transition column: tc[i] = trans[wbase+i][lane]  (coalesced per wave)
    float tc[16];
#pragma unroll
    for (int i = 0; i < 16; ++i)
        tc[i] = trans[(wbase + i) * LBL + lane];

    const float* Xb = X + (size_t)b * TT * LBL;

    // emission prefetch ring (cover HBM latency across barriers)
    float e0 = Xb[0 * LBL + lane];
    float e1 = Xb[1 * LBL + lane];
    float e2 = Xb[2 * LBL + lane];
    float e3 = Xb[3 * LBL + lane];

    // init viterbi vars (t = -1)
    float fvv = (lane == BOS) ? 0.0f : NEGV;

    for (int t = 0; t < TT; ++t) {
        // ---- partial argmax over prev in [wbase, wbase+16) ----
        // strict '>' with ascending index => first-occurrence tie-break (np.argmax)
        float best = __int_as_float(
            __builtin_amdgcn_readlane(__float_as_int(fvv), wbase)) + tc[0];
        int bi = wbase;
#pragma unroll
        for (int i = 1; i < 16; ++i) {
            float s = __int_as_float(
                __builtin_amdgcn_readlane(__float_as_int(fvv), wbase + i)) + tc[i];
            if (s > best) { best = s; bi = wbase + i; }
        }
        part[t & 1][w][lane] = make_float2(best, __int_as_float(bi));
        __syncthreads();

        // ---- cross-wave reduce (redundant in all waves), ascending wave = first-occurrence ----
        float2 p0 = part[t & 1][0][lane];
        float2 p1 = part[t & 1][1][lane];
        float2 p2 = part[t & 1][2][lane];
        float2 p3 = part[t & 1][3][lane];
        float m = p0.x; int mi = __float_as_int(p0.y);
        if (p1.x > m) { m = p1.x; mi = __float_as_int(p1.y); }
        if (p2.x > m) { m = p2.x; mi = __float_as_int(p2.y); }
        if (p3.x > m) { m = p3.x; mi = __float_as_int(p3.y); }

        if (w == 0) bp[t][lane] = (unsigned char)mi;

        float e = e0; e0 = e1; e1 = e2; e2 = e3;
        if (t + 4 < TT) e3 = Xb[(size_t)(t + 4) * LBL + lane];
        fvv = m + e;   // plain f32 add: bitwise-identical to numpy
        // no second barrier needed: part[t&1] is next overwritten at t+2,
        // which is after barrier(t+1), which is after all reads at step t.
    }

    // ---- termination: term = fv + trans[:, EOS] ----
    float term = fvv + trans[lane * LBL + EOS];
    if (w == 0) termv[lane] = term;
    __syncthreads();

    // ---- argmax + sequential backtrack from LDS (thread 0) ----
    if (tid == 0) {
        float bestv = termv[0]; int bl = 0;
        for (int n = 1; n < LBL; ++n)
            if (termv[n] > bestv) { bestv = termv[n]; bl = n; }
        out[b] = bestv;
        int tag = bl;
        for (int t = TT - 1; t >= 0; --t) {
            path_s[t] = (unsigned char)tag;
            tag = bp[t][tag];
        }
    }
    __syncthreads();

    // coalesced path write (paths as float, per harness float32 output buffer)
    float* po = out + BB + (size_t)b * TT;
    for (int t = tid; t < TT; t += 256)
        po[t] = (float)path_s[t];
}

extern "C" void kernel_launch(void* const* d_in, const int* in_sizes, int n_in,
                              void* d_out, int out_size, void* d_ws, size_t ws_size,
                              hipStream_t stream)
{
    const float* X     = (const float*)d_in[0];   // [256, 1024, 64]
    const float* trans = (const float*)d_in[1];   // [64, 64]
    float* out = (float*)d_out;                   // [256] scores ++ [256*1024] path

    viterbi_kernel<<<dim3(BB), dim3(256), 0, stream>>>(X, trans, out);
}